// Round 1
// baseline (557.492 us; speedup 1.0000x reference)
//
#include <hip/hip_runtime.h>
#include <hip/hip_bf16.h>
#include <math.h>

#define NB 64
#define HW 4096
#define CI 256
#define CO 256
#define NE 8

typedef __bf16 bf16x8 __attribute__((ext_vector_type(8)));
typedef __bf16 bf16x4 __attribute__((ext_vector_type(4)));
typedef float  f32x4  __attribute__((ext_vector_type(4)));

// ---------------- pooling: sum over H*W per (b,c) ----------------
// grid 1024 = 64 b * 16 chunks, block 256. float4 loads, LDS reduce, atomicAdd.
__global__ void pool_kernel(const float* __restrict__ x, float* __restrict__ pooled) {
    int blk = blockIdx.x;
    int b = blk >> 4, chunk = blk & 15;
    int t = threadIdx.x;
    int c4 = t & 63;       // float4 channel group (channels c4*4..+3)
    int rg = t >> 6;       // row subgroup 0..3
    const float4* xp = (const float4*)x;
    size_t base = ((size_t)b * HW + (size_t)chunk * 256) * (CI / 4) + c4;
    float4 acc = make_float4(0.f, 0.f, 0.f, 0.f);
    for (int r = rg; r < 256; r += 4) {
        float4 v = xp[base + (size_t)r * (CI / 4)];
        acc.x += v.x; acc.y += v.y; acc.z += v.z; acc.w += v.w;
    }
    __shared__ float4 red[256];
    red[t] = acc;
    __syncthreads();
    if (t < 64) {
        float4 a = red[t], b2 = red[t + 64], c = red[t + 128], d = red[t + 192];
        float s0 = a.x + b2.x + c.x + d.x;
        float s1 = a.y + b2.y + c.y + d.y;
        float s2 = a.z + b2.z + c.z + d.z;
        float s3 = a.w + b2.w + c.w + d.w;
        atomicAdd(&pooled[b * CI + t * 4 + 0], s0);
        atomicAdd(&pooled[b * CI + t * 4 + 1], s1);
        atomicAdd(&pooled[b * CI + t * 4 + 2], s2);
        atomicAdd(&pooled[b * CI + t * 4 + 3], s3);
    }
}

// ---------------- W prep: W[e][k][n] f32 -> Wt[e][n][k] bf16 ----------------
// grid 128 = 8 e * 4 kt * 4 nt, block 256. LDS transpose tile (pad 65 -> no conflicts).
__global__ void wprep_kernel(const float* __restrict__ W, __bf16* __restrict__ Wt) {
    __shared__ float tile[64][65];
    int e  = blockIdx.x >> 4;
    int kt = (blockIdx.x >> 2) & 3;
    int nt = blockIdx.x & 3;
    for (int i = threadIdx.x; i < 4096; i += 256) {
        int r = i >> 6, c = i & 63;      // r = k-local, c = n-local
        tile[r][c] = W[((size_t)(e * 256 + kt * 64 + r)) * 256 + nt * 64 + c];
    }
    __syncthreads();
    for (int i = threadIdx.x; i < 4096; i += 256) {
        int r = i >> 6, c = i & 63;      // r = n-local, c = k-local
        Wt[((size_t)(e * 256 + nt * 64 + r)) * 256 + kt * 64 + c] = (__bf16)tile[c][r];
    }
}

// ---------------- gating: logits -> argmax -> counts -> lb_loss ----------------
// 1 block, 64 threads (one wave), thread b handles sample b.
__global__ void gate_kernel(const float* __restrict__ pooled,
                            const float* __restrict__ gate_W,
                            const float* __restrict__ gate_b,
                            int* __restrict__ eidx,
                            float* __restrict__ lb_out) {
    int b = threadIdx.x;  // 0..63
    float logit[NE];
#pragma unroll
    for (int e = 0; e < NE; ++e) logit[e] = gate_b[e];
    for (int c = 0; c < CI; ++c) {
        float p = pooled[b * CI + c] * (1.0f / 4096.0f);
#pragma unroll
        for (int e = 0; e < NE; ++e) logit[e] += p * gate_W[c * NE + e];
    }
    int best = 0; float bv = logit[0];
#pragma unroll
    for (int e = 1; e < NE; ++e) {
        if (logit[e] > bv) { bv = logit[e]; best = e; }  // strict > keeps first (jnp.argmax)
    }
    eidx[b] = best;
    float u[NE]; float s = 0.f;
#pragma unroll
    for (int e = 0; e < NE; ++e) {
        unsigned long long m = __ballot(best == e);
        u[e] = (float)__popcll(m) * (1.0f / 64.0f) + 1e-6f;
        s += u[e];
    }
    if (b == 0) {
        float lb = 0.f;
#pragma unroll
        for (int e = 0; e < NE; ++e) {
            float ue = u[e] / s;
            lb += ue * (logf(ue) - logf(0.125f));
        }
        *lb_out = lb;
    }
}

// ---------------- main GEMM: out[b] = x[b] @ W[e_b] + bias[e_b] ----------------
// grid 2048 = 64 b * 32 mtiles(128 rows). 4 waves; wave w owns n in [w*64, w*64+64).
// 16x16x32 bf16 MFMA; A staged fp32->bf16 in LDS [128][40] (pad kills conflicts);
// B frags (bf16x8, contiguous k) straight from L2-resident Wt.
__global__ void __launch_bounds__(256, 2)
moe_gemm(const float* __restrict__ x, const __bf16* __restrict__ Wt,
         const float* __restrict__ bias, const int* __restrict__ eidx,
         float* __restrict__ out) {
    __shared__ __align__(16) __bf16 At[128][40];   // 32 k + 8 pad, row stride 80 B
    int mt = blockIdx.x & 31;
    int b  = blockIdx.x >> 5;
    int e  = eidx[b];
    int tid = threadIdx.x;
    int w = tid >> 6, lane = tid & 63;
    int l15 = lane & 15, l4 = lane >> 4;
    int hw0 = mt * 128;

    // init acc with bias (C/D layout: col = lane&15, row = (lane>>4)*4 + reg)
    f32x4 acc[8][4];
#pragma unroll
    for (int n = 0; n < 4; ++n) {
        float bv = bias[e * CO + w * 64 + n * 16 + l15];
        f32x4 t = {bv, bv, bv, bv};
#pragma unroll
        for (int m = 0; m < 8; ++m) acc[m][n] = t;
    }

    const float4* xp = (const float4*)x;
    size_t xbase = ((size_t)b * HW + hw0) * (CI / 4);   // float4 units
    const bf16x8* wp = (const bf16x8*)Wt;
    // Wt[e][n][k]: frag n at (e*256 + w*64 + n*16 + l15) row, k = ks*32 + l4*8
    int wbase = (e * 256 + w * 64 + l15) * 32 + l4;

    for (int ks = 0; ks < 8; ++ks) {
        // B frags from global (issue before barrier; overlaps wait)
        bf16x8 bf[4];
#pragma unroll
        for (int n = 0; n < 4; ++n) bf[n] = wp[wbase + n * 512 + ks * 4];

        // stage A chunk: 128 rows x 32 k, fp32 -> bf16
#pragma unroll
        for (int i = 0; i < 4; ++i) {
            int u = tid + i * 256;
            int row = u >> 3, q = u & 7;          // q = 4-float group within 32 k
            float4 v = xp[xbase + (size_t)row * (CI / 4) + ks * 8 + q];
            bf16x4 h = {(__bf16)v.x, (__bf16)v.y, (__bf16)v.z, (__bf16)v.w};
            *(bf16x4*)((char*)(&At[0][0]) + row * 80 + q * 8) = h;
        }
        __syncthreads();

#pragma unroll
        for (int m = 0; m < 8; ++m) {
            bf16x8 af = *(const bf16x8*)((const char*)(&At[0][0]) +
                                         (m * 16 + l15) * 80 + l4 * 16);
#pragma unroll
            for (int n = 0; n < 4; ++n)
                acc[m][n] = __builtin_amdgcn_mfma_f32_16x16x32_bf16(af, bf[n], acc[m][n], 0, 0, 0);
        }
        __syncthreads();
    }

    // epilogue: coalesced 64B segments (16 lanes x 4B per row group)
    size_t obase = ((size_t)b * HW + hw0) * CO;
#pragma unroll
    for (int m = 0; m < 8; ++m)
#pragma unroll
        for (int n = 0; n < 4; ++n)
#pragma unroll
            for (int r = 0; r < 4; ++r) {
                int row = m * 16 + l4 * 4 + r;
                int col = w * 64 + n * 16 + l15;
                out[obase + (size_t)row * CO + col] = acc[m][n][r];
            }
}

extern "C" void kernel_launch(void* const* d_in, const int* in_sizes, int n_in,
                              void* d_out, int out_size, void* d_ws, size_t ws_size,
                              hipStream_t stream) {
    const float* x      = (const float*)d_in[0];
    const float* W      = (const float*)d_in[1];
    const float* bias   = (const float*)d_in[2];
    const float* gate_W = (const float*)d_in[3];
    const float* gate_b = (const float*)d_in[4];
    float* out = (float*)d_out;

    char* ws = (char*)d_ws;
    __bf16* Wt    = (__bf16*)ws;                          // 1 MiB
    float*  pooled = (float*)(ws + (1 << 20));            // 64 KiB
    int*    eidx   = (int*)(ws + (1 << 20) + (64 << 10)); // 256 B
    float*  lb_out = out + (size_t)NB * HW * CO;          // last output element

    hipMemsetAsync(pooled, 0, NB * CI * sizeof(float), stream);
    pool_kernel<<<1024, 256, 0, stream>>>(x, pooled);
    wprep_kernel<<<128, 256, 0, stream>>>(W, Wt);
    gate_kernel<<<1, 64, 0, stream>>>(pooled, gate_W, gate_b, eidx, lb_out);
    moe_gemm<<<2048, 256, 0, stream>>>(x, Wt, bias, eidx, out);
}